// Round 1
// baseline (1212.192 us; speedup 1.0000x reference)
//
#include <hip/hip_runtime.h>

#define IN_CH   128
#define D_OUT   128   // OUT_CH*HEADS
#define HEADS   4
#define N_TYPES 4
#define N_CONF  5

// ---------------------------------------------------------------------------
// Kernel A: xt[t][n][d] = sum_i x[n][i] * W[t][i][d]
//           for t==0 additionally out[n][d] = xt[0][n][d] + bias[d]
// Register-tiled fp32 GEMV batch: block=256 threads, 64 nodes per block,
// thread = (tx: 32 d-groups of 4, ty: 8 node-groups of 8) -> acc[8][4].
// ---------------------------------------------------------------------------
__global__ __launch_bounds__(256) void k_linear(const float* __restrict__ x,
                                                const float* __restrict__ W,
                                                const float* __restrict__ bias,
                                                float* __restrict__ xt,
                                                float* __restrict__ out,
                                                int N, int nblocks) {
    __shared__ float Xs[64 * 132];   // 64 nodes x 128, stride 132 (pad)
    __shared__ float Ws[32 * 128];   // 32-i chunk of W[t]

    const int t     = blockIdx.x / nblocks;
    const int nbase = (blockIdx.x % nblocks) * 64;
    const int tid   = threadIdx.x;

    // stage X tile (coalesced float4 reads; OOB nodes -> 0)
    for (int f = tid; f < 2048; f += 256) {
        const int n  = f >> 5;
        const int i4 = (f & 31) * 4;
        float4 v = make_float4(0.f, 0.f, 0.f, 0.f);
        const int ng = nbase + n;
        if (ng < N) v = *(const float4*)(x + (size_t)ng * IN_CH + i4);
        *(float4*)(Xs + n * 132 + i4) = v;
    }

    const int tx = tid & 31;   // d-group: d = 4*tx..4*tx+3
    const int ty = tid >> 5;   // node-group: nodes ty*8 .. ty*8+7

    float acc[8][4];
#pragma unroll
    for (int j = 0; j < 8; j++) {
        acc[j][0] = 0.f; acc[j][1] = 0.f; acc[j][2] = 0.f; acc[j][3] = 0.f;
    }

    const float* Wt = W + (size_t)t * IN_CH * D_OUT;

    for (int ib = 0; ib < 4; ib++) {
        __syncthreads();
        // stage 32x128 chunk of W[t]
        for (int f = tid; f < 1024; f += 256) {
            *(float4*)(Ws + f * 4) = *(const float4*)(Wt + ib * 32 * 128 + f * 4);
        }
        __syncthreads();
#pragma unroll
        for (int ii = 0; ii < 32; ii++) {
            const int i = ib * 32 + ii;
            const float4 w4 = *(const float4*)(Ws + ii * 128 + tx * 4);
#pragma unroll
            for (int j = 0; j < 8; j++) {
                const float xs = Xs[(ty * 8 + j) * 132 + i];  // LDS broadcast
                acc[j][0] += xs * w4.x;
                acc[j][1] += xs * w4.y;
                acc[j][2] += xs * w4.z;
                acc[j][3] += xs * w4.w;
            }
        }
    }

    float4 b4 = make_float4(0.f, 0.f, 0.f, 0.f);
    if (t == 0) b4 = *(const float4*)(bias + tx * 4);

#pragma unroll
    for (int j = 0; j < 8; j++) {
        const int ng = nbase + ty * 8 + j;
        if (ng < N) {
            float4 v = make_float4(acc[j][0], acc[j][1], acc[j][2], acc[j][3]);
            *(float4*)(xt + ((size_t)t * N + ng) * D_OUT + tx * 4) = v;
            if (t == 0) {
                float4 o = make_float4(v.x + b4.x, v.y + b4.y, v.z + b4.z, v.w + b4.w);
                *(float4*)(out + (size_t)ng * D_OUT + tx * 4) = o;
            }
        }
    }
}

// ---------------------------------------------------------------------------
// Kernel B: per-edge attention -> wbuf[e][h] = exp(alpha), atomic denom sum.
// One wave (64 lanes) per edge; lane covers channels 2l,2l+1; 16-lane group
// per head. No segment-max needed: softmax invariant to shift, |alpha|<~5.
// ---------------------------------------------------------------------------
__global__ __launch_bounds__(256) void k_alpha(const float* __restrict__ xt,
                                               const int* __restrict__ src,
                                               const int* __restrict__ dst,
                                               const int* __restrict__ et,
                                               const float* __restrict__ attv,
                                               const float* __restrict__ cprobs,
                                               float* __restrict__ wbuf,
                                               float* __restrict__ denom,
                                               int N, int E) {
    __shared__ float att_s[N_CONF * HEADS * 64];
    __shared__ float pk_s[N_CONF];
    const int tid = threadIdx.x;
    for (int f = tid; f < N_CONF * HEADS * 64; f += 256) att_s[f] = attv[f];
    if (tid == 0) {
        float m = cprobs[0];
        for (int k = 1; k < N_CONF; k++) m = fmaxf(m, cprobs[k]);
        float ex[N_CONF], s = 0.f;
        for (int k = 0; k < N_CONF; k++) { ex[k] = __expf(cprobs[k] - m); s += ex[k]; }
        for (int k = 0; k < N_CONF; k++) pk_s[k] = ex[k] / s;
    }
    __syncthreads();

    const int e_id = blockIdx.x * 4 + (tid >> 6);
    if (e_id >= E) return;
    const int lane = tid & 63;

    const int sj = src[e_id];
    const int di = dst[e_id];
    const int tt = et[e_id];

    const float2 xi = ((const float2*)(xt + ((size_t)tt * N + di) * D_OUT))[lane];
    const float2 xj = ((const float2*)(xt + ((size_t)tt * N + sj) * D_OUT))[lane];

    const int c0 = lane * 2;
    const int h  = c0 >> 5;   // head (32 ch per head)
    const int cc = c0 & 31;

    float sc[N_CONF];
#pragma unroll
    for (int k = 0; k < N_CONF; k++) {
        const float* a = att_s + (k * HEADS + h) * 64;
        sc[k] = xi.x * a[cc] + xi.y * a[cc + 1] + xj.x * a[32 + cc] + xj.y * a[33 + cc];
    }
    // butterfly reduce within each 16-lane (per-head) group
#pragma unroll
    for (int off = 1; off < 16; off <<= 1) {
#pragma unroll
        for (int k = 0; k < N_CONF; k++) sc[k] += __shfl_xor(sc[k], off);
    }

    float alpha = 0.f;
#pragma unroll
    for (int k = 0; k < N_CONF; k++) {
        const float s = sc[k];
        alpha += (s > 0.f ? s : 0.2f * s) * pk_s[k];
    }
    const float w = __expf(alpha);

    if ((lane & 15) == 0) {
        wbuf[(size_t)e_id * HEADS + h] = w;
        atomicAdd(denom + ((size_t)tt * N + di) * HEADS + h, w);
    }
}

// ---------------------------------------------------------------------------
// Kernel C: per-edge message scatter: out[dst] += xj * (w/denom) * imp[et]
// One wave per edge, 2 fp32 atomics per lane.
// ---------------------------------------------------------------------------
__global__ __launch_bounds__(256) void k_scatter(const float* __restrict__ xt,
                                                 const int* __restrict__ src,
                                                 const int* __restrict__ dst,
                                                 const int* __restrict__ et,
                                                 const float* __restrict__ imp,
                                                 const float* __restrict__ wbuf,
                                                 const float* __restrict__ denom,
                                                 float* __restrict__ out,
                                                 int N, int E) {
    const int tid  = threadIdx.x;
    const int e_id = blockIdx.x * 4 + (tid >> 6);
    if (e_id >= E) return;
    const int lane = tid & 63;

    const int sj = src[e_id];
    const int di = dst[e_id];
    const int tt = et[e_id];

    const int c0 = lane * 2;
    const int h  = c0 >> 5;

    const float w   = wbuf[(size_t)e_id * HEADS + h];
    const float den = denom[((size_t)tt * N + di) * HEADS + h];
    const float coef = (w / den) * imp[tt];

    const float2 xj = ((const float2*)(xt + ((size_t)tt * N + sj) * D_OUT))[lane];
    atomicAdd(out + (size_t)di * D_OUT + c0,     xj.x * coef);
    atomicAdd(out + (size_t)di * D_OUT + c0 + 1, xj.y * coef);
}

// ---------------------------------------------------------------------------
extern "C" void kernel_launch(void* const* d_in, const int* in_sizes, int n_in,
                              void* d_out, int out_size, void* d_ws, size_t ws_size,
                              hipStream_t stream) {
    const float* x    = (const float*)d_in[0];
    const int*   ei   = (const int*)d_in[1];
    const int*   et   = (const int*)d_in[2];
    const float* W    = (const float*)d_in[3];
    const float* attv = (const float*)d_in[4];
    const float* cpr  = (const float*)d_in[5];
    const float* imp  = (const float*)d_in[6];
    const float* bias = (const float*)d_in[7];

    const int N = in_sizes[0] / IN_CH;
    const int E = in_sizes[2];
    const int* src = ei;        // edge_index[0]
    const int* dst = ei + E;    // edge_index[1]

    float* ws    = (float*)d_ws;
    float* xt    = ws;                                    // T*N*128 floats
    float* wbuf  = xt + (size_t)N_TYPES * N * D_OUT;      // E*H floats
    float* denom = wbuf + (size_t)E * HEADS;              // T*N*H floats
    float* out   = (float*)d_out;

    hipMemsetAsync(denom, 0, (size_t)N_TYPES * N * HEADS * sizeof(float), stream);

    const int nblocks = (N + 63) / 64;
    k_linear<<<dim3(N_TYPES * nblocks), 256, 0, stream>>>(x, W, bias, xt, out, N, nblocks);

    const int eblocks = (E + 3) / 4;
    k_alpha<<<eblocks, 256, 0, stream>>>(xt, src, dst, et, attv, cpr, wbuf, denom, N, E);
    k_scatter<<<eblocks, 256, 0, stream>>>(xt, src, dst, et, imp, wbuf, denom, out, N, E);
}

// Round 2
// 501.736 us; speedup vs baseline: 2.4160x; 2.4160x over previous
//
#include <hip/hip_runtime.h>

#define IN_CH   128
#define D_OUT   128   // OUT_CH*HEADS
#define HEADS   4
#define N_TYPES 4
#define N_CONF  5

// ---------------------------------------------------------------------------
// Kernel A: xt[t][n][d] = sum_i x[n][i] * W[t][i][d]
//           for t==0 additionally out[n][d] = xt[0][n][d] + bias[d]
// ---------------------------------------------------------------------------
__global__ __launch_bounds__(256) void k_linear(const float* __restrict__ x,
                                                const float* __restrict__ W,
                                                const float* __restrict__ bias,
                                                float* __restrict__ xt,
                                                float* __restrict__ out,
                                                int N, int nblocks) {
    __shared__ float Xs[64 * 132];   // 64 nodes x 128, stride 132 (pad)
    __shared__ float Ws[32 * 128];   // 32-i chunk of W[t]

    const int t     = blockIdx.x / nblocks;
    const int nbase = (blockIdx.x % nblocks) * 64;
    const int tid   = threadIdx.x;

    for (int f = tid; f < 2048; f += 256) {
        const int n  = f >> 5;
        const int i4 = (f & 31) * 4;
        float4 v = make_float4(0.f, 0.f, 0.f, 0.f);
        const int ng = nbase + n;
        if (ng < N) v = *(const float4*)(x + (size_t)ng * IN_CH + i4);
        *(float4*)(Xs + n * 132 + i4) = v;
    }

    const int tx = tid & 31;   // d-group: d = 4*tx..4*tx+3
    const int ty = tid >> 5;   // node-group: nodes ty*8 .. ty*8+7

    float acc[8][4];
#pragma unroll
    for (int j = 0; j < 8; j++) {
        acc[j][0] = 0.f; acc[j][1] = 0.f; acc[j][2] = 0.f; acc[j][3] = 0.f;
    }

    const float* Wt = W + (size_t)t * IN_CH * D_OUT;

    for (int ib = 0; ib < 4; ib++) {
        __syncthreads();
        for (int f = tid; f < 1024; f += 256) {
            *(float4*)(Ws + f * 4) = *(const float4*)(Wt + ib * 32 * 128 + f * 4);
        }
        __syncthreads();
#pragma unroll
        for (int ii = 0; ii < 32; ii++) {
            const int i = ib * 32 + ii;
            const float4 w4 = *(const float4*)(Ws + ii * 128 + tx * 4);
#pragma unroll
            for (int j = 0; j < 8; j++) {
                const float xs = Xs[(ty * 8 + j) * 132 + i];
                acc[j][0] += xs * w4.x;
                acc[j][1] += xs * w4.y;
                acc[j][2] += xs * w4.z;
                acc[j][3] += xs * w4.w;
            }
        }
    }

    float4 b4 = make_float4(0.f, 0.f, 0.f, 0.f);
    if (t == 0) b4 = *(const float4*)(bias + tx * 4);

#pragma unroll
    for (int j = 0; j < 8; j++) {
        const int ng = nbase + ty * 8 + j;
        if (ng < N) {
            float4 v = make_float4(acc[j][0], acc[j][1], acc[j][2], acc[j][3]);
            *(float4*)(xt + ((size_t)t * N + ng) * D_OUT + tx * 4) = v;
            if (t == 0) {
                float4 o = make_float4(v.x + b4.x, v.y + b4.y, v.z + b4.z, v.w + b4.w);
                *(float4*)(out + (size_t)ng * D_OUT + tx * 4) = o;
            }
        }
    }
}

// ---------------------------------------------------------------------------
// CSR build: histogram -> scan -> fill (edge packed as src | type<<28)
// ---------------------------------------------------------------------------
__global__ __launch_bounds__(256) void k_hist(const int* __restrict__ dst,
                                              int* __restrict__ counts, int E) {
    const int e = blockIdx.x * 256 + threadIdx.x;
    if (e < E) atomicAdd(&counts[dst[e]], 1);
}

// per-1024-chunk partial sums
__global__ __launch_bounds__(256) void k_scan_part(const int* __restrict__ counts,
                                                   int* __restrict__ partial, int N) {
    __shared__ int s[256];
    const int b = blockIdx.x, t = threadIdx.x;
    const int base = b * 1024 + t * 4;
    int sum = 0;
#pragma unroll
    for (int i = 0; i < 4; i++) if (base + i < N) sum += counts[base + i];
    s[t] = sum; __syncthreads();
    for (int off = 128; off > 0; off >>= 1) {
        if (t < off) s[t] += s[t + off];
        __syncthreads();
    }
    if (t == 0) partial[b] = s[0];
}

__global__ void k_scan_partials(int* partial, int nb) {
    if (threadIdx.x == 0 && blockIdx.x == 0) {
        int run = 0;
        for (int i = 0; i < nb; i++) { int c = partial[i]; partial[i] = run; run += c; }
    }
}

__global__ __launch_bounds__(256) void k_scan_chunk(const int* __restrict__ counts,
                                                    const int* __restrict__ partial,
                                                    int* __restrict__ offsets,
                                                    int* __restrict__ cursor, int N) {
    __shared__ int s[256];
    const int b = blockIdx.x, t = threadIdx.x;
    const int base = b * 1024 + t * 4;
    int v[4]; int sum = 0;
#pragma unroll
    for (int i = 0; i < 4; i++) { v[i] = (base + i < N) ? counts[base + i] : 0; sum += v[i]; }
    s[t] = sum; __syncthreads();
    // inclusive Hillis-Steele over 256 thread-sums
    for (int off = 1; off < 256; off <<= 1) {
        int x = (t >= off) ? s[t - off] : 0;
        __syncthreads();
        s[t] += x;
        __syncthreads();
    }
    int run = partial[b] + s[t] - sum;   // exclusive prefix for this thread
#pragma unroll
    for (int i = 0; i < 4; i++) {
        const int idx = base + i;
        if (idx < N) { offsets[idx] = run; cursor[idx] = run; run += v[i]; }
    }
}

__global__ __launch_bounds__(256) void k_fill(const int* __restrict__ src,
                                              const int* __restrict__ dst,
                                              const int* __restrict__ et,
                                              int* __restrict__ cursor,
                                              int* __restrict__ epack, int E) {
    const int e = blockIdx.x * 256 + threadIdx.x;
    if (e < E) {
        const int pos = atomicAdd(&cursor[dst[e]], 1);
        epack[pos] = src[e] | (et[e] << 28);
    }
}

// ---------------------------------------------------------------------------
// Kernel D: one wave per dst node. Single pass over its in-edges:
//   w = exp(alpha(e)); per-type register accumulators A_t += xj*w, den_t += w
//   out[d] += sum_t A_t * imp[t] / den_t      (no atomics anywhere)
// lane covers channels 2l,2l+1; 16-lane group per head.
// ---------------------------------------------------------------------------
__global__ __launch_bounds__(256) void k_node(const float* __restrict__ xt,
                                              const int* __restrict__ offsets,
                                              const int* __restrict__ counts,
                                              const int* __restrict__ epack,
                                              const float* __restrict__ attv,
                                              const float* __restrict__ cprobs,
                                              const float* __restrict__ imp,
                                              float* __restrict__ out,
                                              int N) {
    __shared__ float att_s[N_CONF * HEADS * 64];
    __shared__ float pk_s[N_CONF];
    __shared__ float imp_s[N_TYPES];
    const int tid = threadIdx.x;
    for (int f = tid; f < N_CONF * HEADS * 64; f += 256) att_s[f] = attv[f];
    if (tid < N_TYPES) imp_s[tid] = imp[tid];
    if (tid == 0) {
        float m = cprobs[0];
        for (int k = 1; k < N_CONF; k++) m = fmaxf(m, cprobs[k]);
        float ex[N_CONF], s = 0.f;
        for (int k = 0; k < N_CONF; k++) { ex[k] = __expf(cprobs[k] - m); s += ex[k]; }
        for (int k = 0; k < N_CONF; k++) pk_s[k] = ex[k] / s;
    }
    __syncthreads();

    const int node = blockIdx.x * 4 + (tid >> 6);
    if (node >= N) return;
    const int lane = tid & 63;
    const int c0 = lane * 2;
    const int h  = c0 >> 5;
    const int cc = c0 & 31;

    // preload this node's own transformed features for all 4 types
    float2 xi_t[N_TYPES];
#pragma unroll
    for (int t = 0; t < N_TYPES; t++)
        xi_t[t] = ((const float2*)(xt + ((size_t)t * N + node) * D_OUT))[lane];

    float accx[N_TYPES], accy[N_TYPES], den[N_TYPES];
#pragma unroll
    for (int t = 0; t < N_TYPES; t++) { accx[t] = 0.f; accy[t] = 0.f; den[t] = 0.f; }

    const int start = offsets[node];
    const int deg   = counts[node];

    for (int k = 0; k < deg; k++) {
        const int pack = epack[start + k];           // wave-uniform load
        const int sj = pack & 0x0FFFFFFF;
        const int tt = (int)((unsigned)pack >> 28);

        const float2 xj = ((const float2*)(xt + ((size_t)tt * N + sj) * D_OUT))[lane];
        float2 xi;
#pragma unroll
        for (int t = 0; t < N_TYPES; t++) if (tt == t) xi = xi_t[t];

        float sc[N_CONF];
#pragma unroll
        for (int q = 0; q < N_CONF; q++) {
            const float* a = att_s + (q * HEADS + h) * 64;
            sc[q] = xi.x * a[cc] + xi.y * a[cc + 1] + xj.x * a[32 + cc] + xj.y * a[33 + cc];
        }
#pragma unroll
        for (int off = 1; off < 16; off <<= 1) {
#pragma unroll
            for (int q = 0; q < N_CONF; q++) sc[q] += __shfl_xor(sc[q], off);
        }
        float alpha = 0.f;
#pragma unroll
        for (int q = 0; q < N_CONF; q++) {
            const float s = sc[q];
            alpha += (s > 0.f ? s : 0.2f * s) * pk_s[q];
        }
        const float w = __expf(alpha);
#pragma unroll
        for (int t = 0; t < N_TYPES; t++) {
            if (tt == t) { accx[t] += xj.x * w; accy[t] += xj.y * w; den[t] += w; }
        }
    }

    float o0 = 0.f, o1 = 0.f;
#pragma unroll
    for (int t = 0; t < N_TYPES; t++) {
        if (den[t] > 0.f) {
            const float f = imp_s[t] / den[t];
            o0 += accx[t] * f;
            o1 += accy[t] * f;
        }
    }
    out[(size_t)node * D_OUT + c0]     += o0;
    out[(size_t)node * D_OUT + c0 + 1] += o1;
}

// ---------------------------------------------------------------------------
extern "C" void kernel_launch(void* const* d_in, const int* in_sizes, int n_in,
                              void* d_out, int out_size, void* d_ws, size_t ws_size,
                              hipStream_t stream) {
    const float* x    = (const float*)d_in[0];
    const int*   ei   = (const int*)d_in[1];
    const int*   et   = (const int*)d_in[2];
    const float* W    = (const float*)d_in[3];
    const float* attv = (const float*)d_in[4];
    const float* cpr  = (const float*)d_in[5];
    const float* imp  = (const float*)d_in[6];
    const float* bias = (const float*)d_in[7];

    const int N = in_sizes[0] / IN_CH;
    const int E = in_sizes[2];
    const int* src = ei;        // edge_index[0]
    const int* dst = ei + E;    // edge_index[1]

    char* ws = (char*)d_ws;
    float* xt      = (float*)ws;                         ws += (size_t)N_TYPES * N * D_OUT * sizeof(float);
    int*   counts  = (int*)ws;                           ws += (size_t)N * sizeof(int);
    int*   offsets = (int*)ws;                           ws += (size_t)N * sizeof(int);
    int*   cursor  = (int*)ws;                           ws += (size_t)N * sizeof(int);
    int*   partial = (int*)ws;                           ws += 64 * sizeof(int);
    int*   epack   = (int*)ws;                           ws += (size_t)E * sizeof(int);
    float* out = (float*)d_out;

    hipMemsetAsync(counts, 0, (size_t)N * sizeof(int), stream);

    const int nblocks = (N + 63) / 64;
    k_linear<<<dim3(N_TYPES * nblocks), 256, 0, stream>>>(x, W, bias, xt, out, N, nblocks);

    const int eb = (E + 255) / 256;
    const int nb = (N + 1023) / 1024;
    k_hist<<<eb, 256, 0, stream>>>(dst, counts, E);
    k_scan_part<<<nb, 256, 0, stream>>>(counts, partial, N);
    k_scan_partials<<<1, 64, 0, stream>>>(partial, nb);
    k_scan_chunk<<<nb, 256, 0, stream>>>(counts, partial, offsets, cursor, N);
    k_fill<<<eb, 256, 0, stream>>>(src, dst, et, cursor, epack, E);

    k_node<<<(N + 3) / 4, 256, 0, stream>>>(xt, offsets, counts, epack, attv, cpr, imp, out, N);
}